// Round 3
// baseline (219.810 us; speedup 1.0000x reference)
//
#include <hip/hip_runtime.h>

// Y = (Bm@A) @ a_term + (Bm@C) @ c_term as one bf16 MFMA GEMM.
// k interleaved: k=2e -> a-part (M), k=2e+1 -> c-part (M2); K=128.
// 8 points/wave, wave-private LDS (no __syncthreads), 2048 blocks.
// Z row = 68 dwords (272 B = 17*16B): conflict-free b128 B-frag reads.
// Epilogue LDS point stride 196 dwords (== 4 mod 32): conflict-free scatter.

typedef __bf16 bf16x8 __attribute__((ext_vector_type(8)));
typedef float floatx4 __attribute__((ext_vector_type(4)));

#define RSW 68  // Z row stride in dwords

__global__ __launch_bounds__(256) void prep_kernel(const float* __restrict__ A,
                                                   const float* __restrict__ Bm,
                                                   const float* __restrict__ C,
                                                   __bf16* __restrict__ acat) {
    int tid = blockIdx.x * 256 + threadIdx.x;  // 0..4095
    int f = tid >> 6;
    int e = tid & 63;
    float m = 0.f, m2 = 0.f;
    #pragma unroll 8
    for (int k = 0; k < 64; ++k) {
        float b = Bm[f * 64 + k];
        m  = fmaf(b, A[k * 64 + e], m);
        m2 = fmaf(b, C[k * 64 + e], m2);
    }
    acat[f * 128 + 2 * e]     = (__bf16)m;   // k = 2e   : M[f,e]
    acat[f * 128 + 2 * e + 1] = (__bf16)m2;  // k = 2e+1 : M2[f,e]
}

static __device__ __forceinline__ unsigned pk(float a, float c) {
    unsigned short ua = __builtin_bit_cast(unsigned short, (__bf16)a);
    unsigned short uc = __builtin_bit_cast(unsigned short, (__bf16)c);
    return ((unsigned)uc << 16) | ua;
}

__global__ __launch_bounds__(256, 5) void main_kernel(const float* __restrict__ X,
                                                      const float* __restrict__ J,
                                                      const __bf16* __restrict__ acat,
                                                      float* __restrict__ out) {
    // per-wave region: Z = 24 rows x 68 dwords = 6528 B (>= epilogue 1564 dwords... fits)
    __shared__ __align__(16) float buf[4][1632];  // 26112 B total -> 6 blocks/CU

    const int wave = threadIdx.x >> 6;
    const int lane = threadIdx.x & 63;
    const int l15  = lane & 15;
    const int quad = lane >> 4;
    const int pbase = blockIdx.x * 32 + wave * 8;  // 8 points per wave

    unsigned* zw = (unsigned*)buf[wave];

    // ---- phase 1: geometry, lane = d ----
    #pragma unroll 4
    for (int pi = 0; pi < 8; ++pi) {
        const size_t p = (size_t)(pbase + pi);
        const float2* jp = (const float2*)(J + p * 384) + lane * 3;
        float2 ja = jp[0], jb = jp[1], jc = jp[2];
        const float* xp = X + p * 192 + lane * 3;
        float xx = xp[0], xy = xp[1], xz = xp[2];

        float a0x = ja.x, a0y = jb.x, a0z = jc.x;  // J col 0
        float a1x = ja.y, a1y = jb.y, a1z = jc.y;  // J col 1

        float n0 = sqrtf(a0x * a0x + a0y * a0y + a0z * a0z);
        float r0 = 1.0f / fmaxf(n0, 1e-12f);
        float b1x = a0x * r0, b1y = a0y * r0, b1z = a0z * r0;

        float d  = b1x * a1x + b1y * a1y + b1z * a1z;
        float ux = a1x - d * b1x, uy = a1y - d * b1y, uz = a1z - d * b1z;
        float n2 = sqrtf(ux * ux + uy * uy + uz * uz);
        float r2 = 1.0f / fmaxf(n2, 1e-12f);
        float b2x = ux * r2, b2y = uy * r2, b2z = uz * r2;

        float b3x = b1y * b2z - b1z * b2y;
        float b3y = b1z * b2x - b1x * b2z;
        float b3z = b1x * b2y - b1y * b2x;

        float rt0 = b1x * xx + b1y * xy + b1z * xz;
        float rt1 = b2x * xx + b2y * xy + b2z * xz;
        float rt2 = b3x * xx + b3y * xy + b3z * xz;

        float s = rt1 - rt2, t = rt1 + rt2;

        // Z[n][k]: n = pi*3+i; lane d writes packed (a_d, c_d) at dword d
        unsigned* zr = zw + (pi * 3) * RSW;
        zr[lane]           = pk(b2x * s + b3x * t, b1x * rt0);
        zr[RSW + lane]     = pk(b2y * s + b3y * t, b1y * rt0);
        zr[2 * RSW + lane] = pk(b2z * s + b3z * t, b1z * rt0);
    }

    // ---- A-fragments (loaded after phase1 to cut live registers) ----
    bf16x8 afrag[4][4];
    #pragma unroll
    for (int mt = 0; mt < 4; ++mt)
        #pragma unroll
        for (int kc = 0; kc < 4; ++kc)
            afrag[mt][kc] = *(const bf16x8*)(acat + (mt * 16 + l15) * 128 + kc * 32 + quad * 8);

    __asm__ volatile("s_waitcnt lgkmcnt(0)" ::: "memory");

    // ---- phase 2: 32x mfma 16x16x32, K=128, n-tiles {0..15},{16..23 valid} ----
    floatx4 acc[4][2];
    #pragma unroll
    for (int mt = 0; mt < 4; ++mt)
        #pragma unroll
        for (int nt = 0; nt < 2; ++nt)
            acc[mt][nt] = (floatx4){0.f, 0.f, 0.f, 0.f};

    #pragma unroll
    for (int kc = 0; kc < 4; ++kc) {
        #pragma unroll
        for (int nt = 0; nt < 2; ++nt) {
            int row = nt * 16 + l15;
            row = row > 23 ? 23 : row;  // clamp: n>=24 columns are garbage, never stored
            bf16x8 b = *(const bf16x8*)((const __bf16*)zw + row * 136 + kc * 32 + quad * 8);
            #pragma unroll
            for (int mt = 0; mt < 4; ++mt)
                acc[mt][nt] = __builtin_amdgcn_mfma_f32_16x16x32_bf16(
                    afrag[mt][kc], b, acc[mt][nt], 0, 0, 0);
        }
    }

    __asm__ volatile("s_waitcnt lgkmcnt(0)" ::: "memory");

    // ---- epilogue: D[f][n] -> LDS [p_local*196 + f*3 + i] (stride 196 == 4 mod 32) ----
    float* dl = buf[wave];
    #pragma unroll
    for (int mt = 0; mt < 4; ++mt) {
        #pragma unroll
        for (int nt = 0; nt < 2; ++nt) {
            int n = nt * 16 + l15;
            if (n < 24) {
                int pl = (n * 21846) >> 16;  // n / 3
                int i  = n - pl * 3;
                float* dst = dl + pl * 196 + i;
                #pragma unroll
                for (int r = 0; r < 4; ++r) {
                    int f = mt * 16 + quad * 4 + r;
                    dst[f * 3] = acc[mt][nt][r];
                }
            }
        }
    }

    __asm__ volatile("s_waitcnt lgkmcnt(0)" ::: "memory");

    // ---- coalesced store: 8 points x 48 float4 = 384 float4 ----
    floatx4* og = (floatx4*)(out + (size_t)pbase * 192);
    #pragma unroll
    for (int t = 0; t < 6; ++t) {
        int g  = t * 64 + lane;          // global float4 index within the 8 points
        int pg = (g * 1366) >> 16;       // g / 48
        int o  = g - pg * 48;
        og[g] = *(const floatx4*)(dl + pg * 196 + o * 4);
    }
}

extern "C" void kernel_launch(void* const* d_in, const int* in_sizes, int n_in,
                              void* d_out, int out_size, void* d_ws, size_t ws_size,
                              hipStream_t stream) {
    const float* X  = (const float*)d_in[0];
    const float* J  = (const float*)d_in[1];
    const float* A  = (const float*)d_in[2];
    const float* Bm = (const float*)d_in[3];
    const float* C  = (const float*)d_in[4];
    float* out = (float*)d_out;
    __bf16* acat = (__bf16*)d_ws;  // 64x128 bf16 = 16 KB

    prep_kernel<<<16, 256, 0, stream>>>(A, Bm, C, acat);

    // 65536 points = 2048 blocks x 4 waves x 8 points
    main_kernel<<<2048, 256, 0, stream>>>(X, J, acat, out);
}

// Round 4
// 209.213 us; speedup vs baseline: 1.0507x; 1.0507x over previous
//
#include <hip/hip_runtime.h>

// Y = (Bm@A) @ a_term + (Bm@C) @ c_term as one bf16 MFMA GEMM.
// R4: kill redundant L1 line-requests. J/X are staged per 4-point tile into
// LDS with fully-coalesced float4 stream loads (each global line touched
// exactly once); the 24-B-record gather happens in LDS instead of at L1.
// Wave-private LDS throughout (no __syncthreads).
// Per-wave LDS (floats): [0..1535] J stage / epilogue reuse, [1536..2303] X stage,
//                        [2304..3119] Z (12 rows x 68 dwords, 272 B rows).

typedef __bf16 bf16x8 __attribute__((ext_vector_type(8)));
typedef float floatx4 __attribute__((ext_vector_type(4)));

#define RSW 68  // Z row stride in dwords

__global__ __launch_bounds__(256) void prep_kernel(const float* __restrict__ A,
                                                   const float* __restrict__ Bm,
                                                   const float* __restrict__ C,
                                                   __bf16* __restrict__ acat) {
    int tid = blockIdx.x * 256 + threadIdx.x;  // 0..4095
    int f = tid >> 6;
    int e = tid & 63;
    float m = 0.f, m2 = 0.f;
    #pragma unroll 8
    for (int k = 0; k < 64; ++k) {
        float b = Bm[f * 64 + k];
        m  = fmaf(b, A[k * 64 + e], m);
        m2 = fmaf(b, C[k * 64 + e], m2);
    }
    acat[f * 128 + 2 * e]     = (__bf16)m;   // k = 2e   : M[f,e]
    acat[f * 128 + 2 * e + 1] = (__bf16)m2;  // k = 2e+1 : M2[f,e]
}

static __device__ __forceinline__ unsigned pk(float a, float c) {
    unsigned short ua = __builtin_bit_cast(unsigned short, (__bf16)a);
    unsigned short uc = __builtin_bit_cast(unsigned short, (__bf16)c);
    return ((unsigned)uc << 16) | ua;
}

__global__ __launch_bounds__(256, 3) void main_kernel(const float* __restrict__ X,
                                                      const float* __restrict__ J,
                                                      const __bf16* __restrict__ acat,
                                                      float* __restrict__ out) {
    __shared__ __align__(16) float buf[4][3120];  // 49,920 B -> 3 blocks/CU

    const int wave = threadIdx.x >> 6;
    const int lane = threadIdx.x & 63;
    const int l15  = lane & 15;
    const int quad = lane >> 4;
    const int pbase = blockIdx.x * 16 + wave * 4;  // 4 points per wave

    float* stg = buf[wave];

    // ---- stage J (384 f4) and X (192 f4) coalesced: every line touched once ----
    {
        const floatx4* jg = (const floatx4*)(J + (size_t)pbase * 384);
        const floatx4* xg = (const floatx4*)(X + (size_t)pbase * 192);
        floatx4 jt[6], xt[3];
        #pragma unroll
        for (int t = 0; t < 6; ++t) jt[t] = jg[t * 64 + lane];
        #pragma unroll
        for (int t = 0; t < 3; ++t) xt[t] = xg[t * 64 + lane];
        floatx4* sj = (floatx4*)stg;
        floatx4* sx = (floatx4*)(stg + 1536);
        #pragma unroll
        for (int t = 0; t < 6; ++t) sj[t * 64 + lane] = jt[t];
        #pragma unroll
        for (int t = 0; t < 3; ++t) sx[t * 64 + lane] = xt[t];
    }

    __asm__ volatile("s_waitcnt lgkmcnt(0)" ::: "memory");

    unsigned* zw = (unsigned*)(stg + 2304);

    // ---- phase 1: geometry, lane = d, records gathered from LDS ----
    #pragma unroll
    for (int pi = 0; pi < 4; ++pi) {
        const float* jst = stg + pi * 384 + lane * 6;
        float2 ja = *(const float2*)(jst);
        float2 jb = *(const float2*)(jst + 2);
        float2 jc = *(const float2*)(jst + 4);
        const float* xst = stg + 1536 + pi * 192 + lane * 3;
        float xx = xst[0], xy = xst[1], xz = xst[2];

        // record layout: [i][j] row-major -> ja=(r0c0,r0c1), jb=(r1c0,r1c1), jc=r2
        float a0x = ja.x, a0y = jb.x, a0z = jc.x;  // J col 0
        float a1x = ja.y, a1y = jb.y, a1z = jc.y;  // J col 1

        float n0 = sqrtf(a0x * a0x + a0y * a0y + a0z * a0z);
        float r0 = 1.0f / fmaxf(n0, 1e-12f);
        float b1x = a0x * r0, b1y = a0y * r0, b1z = a0z * r0;

        float d  = b1x * a1x + b1y * a1y + b1z * a1z;
        float ux = a1x - d * b1x, uy = a1y - d * b1y, uz = a1z - d * b1z;
        float n2 = sqrtf(ux * ux + uy * uy + uz * uz);
        float r2 = 1.0f / fmaxf(n2, 1e-12f);
        float b2x = ux * r2, b2y = uy * r2, b2z = uz * r2;

        float b3x = b1y * b2z - b1z * b2y;
        float b3y = b1z * b2x - b1x * b2z;
        float b3z = b1x * b2y - b1y * b2x;

        float rt0 = b1x * xx + b1y * xy + b1z * xz;
        float rt1 = b2x * xx + b2y * xy + b2z * xz;
        float rt2 = b3x * xx + b3y * xy + b3z * xz;

        float s = rt1 - rt2, t = rt1 + rt2;

        unsigned* zr = zw + (pi * 3) * RSW;
        zr[lane]           = pk(b2x * s + b3x * t, b1x * rt0);
        zr[RSW + lane]     = pk(b2y * s + b3y * t, b1y * rt0);
        zr[2 * RSW + lane] = pk(b2z * s + b3z * t, b1z * rt0);
    }

    // ---- A-fragments (L2-resident 16 KB table) ----
    bf16x8 afrag[4][4];
    #pragma unroll
    for (int mt = 0; mt < 4; ++mt)
        #pragma unroll
        for (int kc = 0; kc < 4; ++kc)
            afrag[mt][kc] = *(const bf16x8*)(acat + (mt * 16 + l15) * 128 + kc * 32 + quad * 8);

    __asm__ volatile("s_waitcnt lgkmcnt(0)" ::: "memory");

    // ---- phase 2: 16x mfma 16x16x32, K=128, rows 0..11 valid ----
    floatx4 acc[4];
    #pragma unroll
    for (int mt = 0; mt < 4; ++mt) acc[mt] = (floatx4){0.f, 0.f, 0.f, 0.f};

    int row = l15 > 11 ? 11 : l15;  // clamp: n>=12 columns are garbage, never stored
    #pragma unroll
    for (int kc = 0; kc < 4; ++kc) {
        bf16x8 b = *(const bf16x8*)((const __bf16*)zw + row * 136 + kc * 32 + quad * 8);
        #pragma unroll
        for (int mt = 0; mt < 4; ++mt)
            acc[mt] = __builtin_amdgcn_mfma_f32_16x16x32_bf16(afrag[mt][kc], b, acc[mt], 0, 0, 0);
    }

    __asm__ volatile("s_waitcnt lgkmcnt(0)" ::: "memory");

    // ---- epilogue: D[f][n] -> LDS [p_local*196 + f*3 + i] (reuse J stage region) ----
    float* dl = stg;
    #pragma unroll
    for (int mt = 0; mt < 4; ++mt) {
        int n = l15;
        if (n < 12) {
            int pl = (n * 21846) >> 16;  // n / 3
            int i  = n - pl * 3;
            float* dst = dl + pl * 196 + i;
            #pragma unroll
            for (int r = 0; r < 4; ++r) {
                int f = mt * 16 + quad * 4 + r;
                dst[f * 3] = acc[mt][r];
            }
        }
    }

    __asm__ volatile("s_waitcnt lgkmcnt(0)" ::: "memory");

    // ---- coalesced store: 4 points x 48 float4 = 192 float4 ----
    floatx4* og = (floatx4*)(out + (size_t)pbase * 192);
    #pragma unroll
    for (int t = 0; t < 3; ++t) {
        int g  = t * 64 + lane;
        int pg = (g * 1366) >> 16;  // g / 48
        int o  = g - pg * 48;
        og[g] = *(const floatx4*)(dl + pg * 196 + o * 4);
    }
}

extern "C" void kernel_launch(void* const* d_in, const int* in_sizes, int n_in,
                              void* d_out, int out_size, void* d_ws, size_t ws_size,
                              hipStream_t stream) {
    const float* X  = (const float*)d_in[0];
    const float* J  = (const float*)d_in[1];
    const float* A  = (const float*)d_in[2];
    const float* Bm = (const float*)d_in[3];
    const float* C  = (const float*)d_in[4];
    float* out = (float*)d_out;
    __bf16* acat = (__bf16*)d_ws;  // 64x128 bf16 = 16 KB

    prep_kernel<<<16, 256, 0, stream>>>(A, Bm, C, acat);

    // 65536 points = 4096 blocks x 4 waves x 4 points
    main_kernel<<<4096, 256, 0, stream>>>(X, J, acat, out);
}